// Round 5
// baseline (425.414 us; speedup 1.0000x reference)
//
#include <hip/hip_runtime.h>
#include <math.h>

#define NB 8192
#define H 1024
#define HH 512
#define NEXP 16
#define NT128 96            // max sum of per-expert ceil(cnt/128), padded
#define AMBIG_THR 1e-3f     // ~50 sigma of split-bf16 logit error

// MFMA 16x16x32 bf16 fragments
typedef __attribute__((ext_vector_type(8))) short bfrag;
typedef __attribute__((ext_vector_type(4))) float f4;

__device__ __forceinline__ f4 MF(bfrag a, bfrag b, f4 c) {
    return __builtin_amdgcn_mfma_f32_16x16x32_bf16(a, b, c, 0, 0, 0);
}
__device__ __forceinline__ unsigned short f2bf(float f) {  // RNE fp32->bf16
    unsigned u = __float_as_uint(f);
    u += 0x7fff + ((u >> 16) & 1);
    return (unsigned short)(u >> 16);
}
__device__ __forceinline__ float bf2f(unsigned short h) {
    return __uint_as_float((unsigned)h << 16);
}
// split-convert 8 floats -> hi/lo bf16 fragments (same arithmetic as old cvtA)
__device__ __forceinline__ void cvt_split8(const float* f, bfrag& hi, bfrag& lo) {
    #pragma unroll
    for (int i = 0; i < 8; ++i) {
        unsigned short h = f2bf(f[i]);
        hi[i] = (short)h;
        lo[i] = (short)f2bf(f[i] - bf2f(h));
    }
}
// hi-only convert (same as old cvtB)
__device__ __forceinline__ bfrag cvt_hi8(const float* f) {
    bfrag r;
    #pragma unroll
    for (int i = 0; i < 8; ++i) r[i] = (short)f2bf(f[i]);
    return r;
}
// read 8 consecutive k-floats of one row from an fp32-staged LDS tile (32 f/row,
// 8 slots of 16B, slot index XOR-swizzled by row&7 on both stage and read sides)
__device__ __forceinline__ void ldf8(const char* rowbase, int f, int quad, float* out) {
    *(float4*)&out[0] = *(const float4*)(rowbase + (((2 * quad)     ^ f) << 4));
    *(float4*)&out[4] = *(const float4*)(rowbase + (((2 * quad + 1) ^ f) << 4));
}

// async global->LDS, 16B per lane; LDS dest is wave-uniform base + lane*16
typedef __attribute__((address_space(1))) const unsigned GAS;
typedef __attribute__((address_space(3))) unsigned LAS;
__device__ __forceinline__ void gld16(const void* g, void* l) {
    __builtin_amdgcn_global_load_lds((GAS*)g, (LAS*)l, 16, 0, 0);
}

// split-conversion of gating weights only: w1 (512 blocks), w3 (8); block 0 zeroes counters
__global__ __launch_bounds__(256) void cvtW_kernel(
    const float* __restrict__ w1, const float* __restrict__ w3,
    unsigned short* __restrict__ w1hi, unsigned short* __restrict__ w1lo,
    unsigned short* __restrict__ w3hi, unsigned short* __restrict__ w3lo,
    int* __restrict__ counts, int* __restrict__ ambig_cnt)
{
    const int b = blockIdx.x, t = threadIdx.x;
    if (b == 0) {
        if (t < NEXP) counts[t] = 0;
        if (t == NEXP) ambig_cnt[0] = 0;
    }
    const float* src; unsigned short *hi, *lo; int i;
    if (b < 512) { src = w1; hi = w1hi; lo = w1lo; i = b * 256 + t; }
    else         { src = w3; hi = w3hi; lo = w3lo; i = (b - 512) * 256 + t; }
    float4 v = ((const float4*)src)[i];
    ushort4 h, l;
    h.x = f2bf(v.x); l.x = f2bf(v.x - bf2f(h.x));
    h.y = f2bf(v.y); l.y = f2bf(v.y - bf2f(h.y));
    h.z = f2bf(v.z); l.z = f2bf(v.z - bf2f(h.z));
    h.w = f2bf(v.w); l.w = f2bf(v.w - bf2f(h.w));
    ((ushort4*)hi)[i] = h;
    ((ushort4*)lo)[i] = l;
}

// ---- gating GEMM1 (split 3-term): x1 = relu(q @ w1^T + b1), stored hi/lo ----
// A (q) staged as RAW FP32 (16KB/buf — same bytes as old Ah+Al) and split to hi/lo
// on LDS read; B staged bf16 hi/lo. Triple-buffered counted-vmcnt pipeline.
// 128x64 tile, BK=32, 4 waves. grid (64, 8). LDS 72KB.
__global__ __launch_bounds__(256) void g1_kernel(
    const float* __restrict__ qf,
    const unsigned short* __restrict__ w1hi, const unsigned short* __restrict__ w1lo,
    const float* __restrict__ b1,
    unsigned short* __restrict__ x1hi, unsigned short* __restrict__ x1lo)
{
    __shared__ float          Aq[3][128][32];   // 48KB
    __shared__ unsigned short Bh[3][64][32];    // 12KB
    __shared__ unsigned short Bl[3][64][32];    // 12KB

    const int t = threadIdx.x, w = t >> 6, lane = t & 63;
    const int quad = lane >> 4, l16 = lane & 15;
    const int rowA0 = blockIdx.x * 128;
    const int colB0 = blockIdx.y * 64;

    // 24 chunks/kt: c 0-15 -> Aq (fp32, 8 rows x 8 slots/chunk), 16-19 Bh, 20-23 Bl
    const char* gsrc[6]; char* lbase[6]; int bstr[6], kst[6];
    #pragma unroll
    for (int j = 0; j < 6; ++j) {
        int c = w + j * 4;
        if (c < 16) {
            int rl = lane >> 3, sl = lane & 7;
            int row = c * 8 + rl;
            gsrc[j] = (const char*)(qf + (size_t)(rowA0 + row) * H + ((sl ^ (row & 7)) << 2));
            lbase[j] = (char*)&Aq[0][c * 8][0];
            bstr[j] = 128 * 32 * 4; kst[j] = 32 * 4;
        } else {
            int rl = lane >> 2, sl = lane & 3;
            int row = ((c - 16) & 3) * 16 + rl;
            int f = (row & 3) ^ ((row >> 2) & 3);
            const unsigned short* s = (c < 20) ? w1hi : w1lo;
            gsrc[j] = (const char*)(s + (size_t)(colB0 + row) * H + ((sl ^ f) << 3));
            lbase[j] = (c < 20) ? (char*)&Bh[0][row - rl + rl][0] : (char*)&Bl[0][row - rl + rl][0];
            lbase[j] = (c < 20) ? (char*)&Bh[0][((c - 16) & 3) * 16][0]
                                : (char*)&Bl[0][((c - 16) & 3) * 16][0];
            bstr[j] = 64 * 32 * 2; kst[j] = 32 * 2;
        }
    }

    const f4 z4 = {0.f, 0.f, 0.f, 0.f};
    f4 acc[2][4] = {{z4, z4, z4, z4}, {z4, z4, z4, z4}};
    const int sw = (quad ^ (l16 & 3) ^ (l16 >> 2)) * 8;   // bf16 B read swizzle
    const int fa = l16 & 7;                                // fp32 A read swizzle
    const int ra0 = w * 32 + l16, ra1 = ra0 + 16;

    auto STAGE = [&](int buf, int kt) {
        #pragma unroll
        for (int j = 0; j < 6; ++j)
            gld16(gsrc[j] + (size_t)kt * kst[j], lbase[j] + (size_t)buf * bstr[j]);
    };
    auto COMPUTE = [&](int buf) {
        float fa0[8], fa1[8];
        ldf8((const char*)&Aq[buf][ra0][0], fa, quad, fa0);
        ldf8((const char*)&Aq[buf][ra1][0], fa, quad, fa1);
        bfrag ah0, al0, ah1, al1;
        cvt_split8(fa0, ah0, al0);
        cvt_split8(fa1, ah1, al1);
        #pragma unroll
        for (int cb = 0; cb < 4; ++cb) {
            bfrag bh = *(const bfrag*)&Bh[buf][cb * 16 + l16][sw];
            bfrag bl = *(const bfrag*)&Bl[buf][cb * 16 + l16][sw];
            acc[0][cb] = MF(al0, bh, MF(ah0, bl, MF(ah0, bh, acc[0][cb])));
            acc[1][cb] = MF(al1, bh, MF(ah1, bl, MF(ah1, bh, acc[1][cb])));
        }
    };

    STAGE(0, 0);
    STAGE(1, 1);
    for (int kt = 0; kt < 32; ++kt) {
        if (kt < 31) asm volatile("s_waitcnt vmcnt(6)" ::: "memory");
        else         asm volatile("s_waitcnt vmcnt(0)" ::: "memory");
        __builtin_amdgcn_s_barrier();
        if (kt < 30) STAGE((kt + 2) % 3, kt + 2);
        COMPUTE(kt % 3);
    }

    const int row0 = rowA0 + w * 32;
    #pragma unroll
    for (int cb = 0; cb < 4; ++cb) {
        int col = colB0 + cb * 16 + l16;
        float bias = b1[col];
        #pragma unroll
        for (int rb = 0; rb < 2; ++rb)
            #pragma unroll
            for (int i = 0; i < 4; ++i) {
                int row = rb * 16 + quad * 4 + i;
                float v = fmaxf(acc[rb][cb][i] + bias, 0.f);
                unsigned short hh = f2bf(v);
                size_t idx = (size_t)(row0 + row) * HH + col;
                x1hi[idx] = hh;
                x1lo[idx] = f2bf(v - bf2f(hh));
            }
    }
}

// ---- logits (split 3-term) + argmax + gate + counts + ambiguity flag ----
__global__ __launch_bounds__(256) void logits_kernel(
    const unsigned short* __restrict__ x1hi, const unsigned short* __restrict__ x1lo,
    const unsigned short* __restrict__ w3hi, const unsigned short* __restrict__ w3lo,
    const float* __restrict__ b3,
    int* __restrict__ top1, float* __restrict__ gval, int* __restrict__ counts,
    int* __restrict__ ambig_rows, int* __restrict__ ambig_cnt)
{
    __shared__ float lgp[4][32][NEXP];
    const int t = threadIdx.x, wave = t >> 6, lane = t & 63;
    const int quad = lane >> 4, l16 = lane & 15;
    const int row0 = blockIdx.x * 32;
    const f4 z4 = {0.f, 0.f, 0.f, 0.f};

    f4 l0 = z4, l1 = z4;
    const size_t ar0 = (size_t)(row0 + l16) * HH + quad * 8;
    const size_t ar1 = ar0 + (size_t)16 * HH;
    const size_t br = (size_t)l16 * HH + quad * 8;
    #pragma unroll
    for (int ks = 0; ks < 4; ++ks) {
        int kk = wave * 128 + ks * 32;
        bfrag ah0 = *(const bfrag*)(x1hi + ar0 + kk);
        bfrag al0 = *(const bfrag*)(x1lo + ar0 + kk);
        bfrag ah1 = *(const bfrag*)(x1hi + ar1 + kk);
        bfrag al1 = *(const bfrag*)(x1lo + ar1 + kk);
        bfrag bh  = *(const bfrag*)(w3hi + br + kk);
        bfrag bl  = *(const bfrag*)(w3lo + br + kk);
        l0 = MF(al0, bh, MF(ah0, bl, MF(ah0, bh, l0)));
        l1 = MF(al1, bh, MF(ah1, bl, MF(ah1, bh, l1)));
    }
    #pragma unroll
    for (int i = 0; i < 4; ++i) {
        lgp[wave][quad * 4 + i][l16] = l0[i];
        lgp[wave][16 + quad * 4 + i][l16] = l1[i];
    }
    __syncthreads();

    if (t < 32) {
        float lg[NEXP];
        #pragma unroll
        for (int m = 0; m < NEXP; ++m)
            lg[m] = lgp[0][t][m] + lgp[1][t][m] + lgp[2][t][m] + lgp[3][t][m] + b3[m];
        float best = lg[0], second = -3.4e38f; int bi = 0;
        #pragma unroll
        for (int m = 1; m < NEXP; ++m) {
            float v = lg[m];
            if (v > best) { second = best; best = v; bi = m; }
            else if (v > second) second = v;
        }
        float se = 0.f;
        #pragma unroll
        for (int m = 0; m < NEXP; ++m) se += expf(lg[m] - best);
        int grow = row0 + t;
        top1[grow] = bi;
        gval[grow] = 1.f / se;
        atomicAdd(&counts[bi], 1);
        if (best - second < AMBIG_THR) {
            int pos = atomicAdd(ambig_cnt, 1);
            if (pos < NB) ambig_rows[pos] = grow;
        }
    }
}

// ---- exact fp32 x1 recompute for ambiguous rows, column-parallel ----
__global__ __launch_bounds__(256) void fixup1_kernel(
    const float* __restrict__ q, const float* __restrict__ w1, const float* __restrict__ b1,
    const int* __restrict__ ambig_rows, const int* __restrict__ ambig_cnt,
    float* __restrict__ x1buf)
{
    __shared__ __align__(16) float qrow[H];
    const int t = threadIdx.x, wv = t >> 6, ln = t & 63;
    const int chunk = blockIdx.x & 7;
    const int slot  = blockIdx.x >> 3;
    const int base  = chunk * 64;
    int nn = *ambig_cnt; if (nn > NB) nn = NB;
    for (int ii = slot; ii < nn; ii += 32) {
        int row = ambig_rows[ii];
        ((float4*)qrow)[t] = ((const float4*)(q + (size_t)row * H))[t];
        __syncthreads();
        for (int c = base + wv * 2; c < base + 64; c += 8) {
            const float4* w0 = (const float4*)(w1 + (size_t)c * H);
            const float4* w1r = (const float4*)(w1 + (size_t)(c + 1) * H);
            const float4* qv = (const float4*)qrow;
            float s0 = 0.f, s1 = 0.f;
            #pragma unroll
            for (int j = 0; j < 4; ++j) {
                float4 a = qv[j * 64 + ln];
                float4 b0 = w0[j * 64 + ln];
                float4 b1v = w1r[j * 64 + ln];
                s0 += a.x * b0.x + a.y * b0.y + a.z * b0.z + a.w * b0.w;
                s1 += a.x * b1v.x + a.y * b1v.y + a.z * b1v.z + a.w * b1v.w;
            }
            #pragma unroll
            for (int off = 32; off; off >>= 1) {
                s0 += __shfl_xor(s0, off, 64);
                s1 += __shfl_xor(s1, off, 64);
            }
            if (ln == 0) {
                x1buf[(size_t)ii * HH + c]     = fmaxf(s0 + b1[c], 0.f);
                x1buf[(size_t)ii * HH + c + 1] = fmaxf(s1 + b1[c + 1], 0.f);
            }
        }
        __syncthreads();
    }
}

// ---- logits from exact x1 + top1/gval/counts update ----
__global__ __launch_bounds__(256) void fixup2_kernel(
    const float* __restrict__ x1buf,
    const float* __restrict__ w3, const float* __restrict__ b3,
    const int* __restrict__ ambig_rows, const int* __restrict__ ambig_cnt,
    int* __restrict__ top1, float* __restrict__ gval, int* __restrict__ counts)
{
    __shared__ float lgs[NEXP];
    const int t = threadIdx.x, wv = t >> 6, ln = t & 63;
    int nn = *ambig_cnt; if (nn > NB) nn = NB;
    for (int ii = blockIdx.x; ii < nn; ii += gridDim.x) {
        int row = ambig_rows[ii];
        const float4* xv = (const float4*)(x1buf + (size_t)ii * HH);
        for (int m = wv; m < NEXP; m += 4) {
            const float4* wr = (const float4*)(w3 + (size_t)m * HH);
            float s = 0.f;
            #pragma unroll
            for (int j = 0; j < 2; ++j) {
                float4 a = xv[j * 64 + ln];
                float4 b = wr[j * 64 + ln];
                s += a.x * b.x + a.y * b.y + a.z * b.z + a.w * b.w;
            }
            #pragma unroll
            for (int off = 32; off; off >>= 1) s += __shfl_xor(s, off, 64);
            if (ln == 0) lgs[m] = s + b3[m];
        }
        __syncthreads();
        if (t == 0) {
            float best = lgs[0]; int bi = 0;
            #pragma unroll
            for (int m = 1; m < NEXP; ++m) if (lgs[m] > best) { best = lgs[m]; bi = m; }
            float se = 0.f;
            #pragma unroll
            for (int m = 0; m < NEXP; ++m) se += expf(lgs[m] - best);
            int old = top1[row];
            if (bi != old) {
                atomicSub(&counts[old], 1);
                atomicAdd(&counts[bi], 1);
                top1[row] = bi;
            }
            gval[row] = 1.f / se;
        }
        __syncthreads();
    }
}

// fused offsets + tile-map + scatter (single block; LDS atomics)
__global__ __launch_bounds__(256) void osc_kernel(
    const int* __restrict__ counts,
    int* __restrict__ tm_e, int* __restrict__ tm_p, int* __restrict__ tm_end,
    const int* __restrict__ top1, int* __restrict__ brows)
{
    __shared__ int sbpos[NEXP];
    const int t = threadIdx.x;
    if (t == 0) {
        int run = 0, tile = 0;
        for (int e = 0; e < NEXP; ++e) {
            sbpos[e] = run;
            int beg = run, end = run + counts[e];
            for (int p = beg; p < end; p += 128) {
                tm_e[tile] = e; tm_p[tile] = p; tm_end[tile] = end; ++tile;
            }
            run = end;
        }
        for (; tile < NT128; ++tile) tm_e[tile] = -1;
    }
    __syncthreads();
    for (int i = t; i < NB; i += 256) {
        int e = top1[i];
        int pos = atomicAdd(&sbpos[e], 1);
        brows[pos] = i;
    }
}

// ---- expert GEMM1: h = relu(q[brows] @ w1[e]^T + b1[e]) ----
// A = gathered q FP32, B = exp_w1 FP32; both converted to bf16 on LDS read
// (bit-identical to old cvt kernels). Triple-buffered counted-vmcnt. grid (NT128, 8).
__global__ __launch_bounds__(256) void exp1_kernel(
    const float* __restrict__ qf, const float* __restrict__ ew1,
    const float* __restrict__ eb1,
    const int* __restrict__ tm_e, const int* __restrict__ tm_p, const int* __restrict__ tm_end,
    const int* __restrict__ brows, unsigned short* __restrict__ h)
{
    const int e = tm_e[blockIdx.x];
    if (e < 0) return;
    const int p0 = tm_p[blockIdx.x], end = tm_end[blockIdx.x];

    __shared__ float Aq[3][128][32];   // 48KB
    __shared__ float Bw[3][64][32];    // 24KB

    const int t = threadIdx.x, w = t >> 6, lane = t & 63;
    const int quad = lane >> 4, l16 = lane & 15;
    const int c0 = blockIdx.y * 64;
    const float* w1p = ew1 + (size_t)e * HH * H;
    const int rl = lane >> 3, sl = lane & 7;

    // 24 chunks/kt: c 0-15 -> Aq rows c*8.., c 16-23 -> Bw rows (c-16)*8..
    const char* gsrc[6]; char* lbase[6]; int bstr[6];
    #pragma unroll
    for (int j = 0; j < 6; ++j) {
        int c = w + j * 4;
        if (c < 16) {
            int row = c * 8 + rl;
            int pa = p0 + row; if (pa >= end) pa = end - 1;
            gsrc[j] = (const char*)(qf + (size_t)brows[pa] * H + ((sl ^ (row & 7)) << 2));
            lbase[j] = (char*)&Aq[0][c * 8][0];
            bstr[j] = 128 * 32 * 4;
        } else {
            int row = (c - 16) * 8 + rl;
            gsrc[j] = (const char*)(w1p + (size_t)(c0 + row) * H + ((sl ^ (row & 7)) << 2));
            lbase[j] = (char*)&Bw[0][(c - 16) * 8][0];
            bstr[j] = 64 * 32 * 4;
        }
    }

    const f4 z4 = {0.f, 0.f, 0.f, 0.f};
    f4 acc[2][4] = {{z4, z4, z4, z4}, {z4, z4, z4, z4}};
    const int fa = l16 & 7;
    const int ra0 = w * 32 + l16, ra1 = ra0 + 16;

    auto STAGE = [&](int buf, int kt) {
        #pragma unroll
        for (int j = 0; j < 6; ++j)
            gld16(gsrc[j] + (size_t)kt * 128, lbase[j] + (size_t)buf * bstr[j]);
    };
    auto COMPUTE = [&](int buf) {
        float f0[8], f1[8];
        ldf8((const char*)&Aq[buf][ra0][0], fa, quad, f0);
        ldf8((const char*)&Aq[buf][ra1][0], fa, quad, f1);
        bfrag a0 = cvt_hi8(f0), a1 = cvt_hi8(f1);
        #pragma unroll
        for (int cb = 0; cb < 4; ++cb) {
            float fb[8];
            ldf8((const char*)&Bw[buf][cb * 16 + l16][0], fa, quad, fb);
            bfrag bb = cvt_hi8(fb);
            acc[0][cb] = MF(a0, bb, acc[0][cb]);
            acc[1][cb] = MF(a1, bb, acc[1][cb]);
        }
    };

    STAGE(0, 0);
    STAGE(1, 1);
    for (int kt = 0; kt < 32; ++kt) {
        if (kt < 31) asm volatile("s_waitcnt vmcnt(6)" ::: "memory");
        else         asm volatile("s_waitcnt vmcnt(0)" ::: "memory");
        __builtin_amdgcn_s_barrier();
        if (kt < 30) STAGE((kt + 2) % 3, kt + 2);
        COMPUTE(kt % 3);
    }

    const int prow0 = p0 + w * 32;
    #pragma unroll
    for (int cb = 0; cb < 4; ++cb) {
        int col = c0 + cb * 16 + l16;
        float bias = eb1[e * HH + col];
        #pragma unroll
        for (int rb = 0; rb < 2; ++rb)
            #pragma unroll
            for (int i = 0; i < 4; ++i) {
                int row = rb * 16 + quad * 4 + i;
                if (prow0 + row < end)
                    h[(size_t)(prow0 + row) * HH + col] = f2bf(fmaxf(acc[rb][cb][i] + bias, 0.f));
            }
    }
}

// ---- expert GEMM2: v = h @ w2[e]^T + b2[e]; psum = partial sum v^2 ----
// A = hbuf bf16 (old swizzle), B = exp_w2 FP32 converted on read. grid (NT128, 16).
__global__ __launch_bounds__(256) void exp2_kernel(
    const unsigned short* __restrict__ h, const float* __restrict__ ew2,
    const float* __restrict__ eb2,
    const int* __restrict__ tm_e, const int* __restrict__ tm_p, const int* __restrict__ tm_end,
    const int* __restrict__ brows,
    float* __restrict__ vout, float* __restrict__ psum)
{
    const int e = tm_e[blockIdx.x];
    if (e < 0) return;
    const int p0 = tm_p[blockIdx.x], end = tm_end[blockIdx.x];

    __shared__ unsigned short Ah[3][128][32];  // 24KB
    __shared__ float          Bw[3][64][32];   // 24KB

    const int t = threadIdx.x, w = t >> 6, lane = t & 63;
    const int quad = lane >> 4, l16 = lane & 15;
    const int cg = blockIdx.y;
    const int c0 = cg * 64;
    const float* w2p = ew2 + (size_t)e * H * HH;

    // 16 chunks/kt: c 0-7 -> Ah (bf16, 16 rows/chunk), c 8-15 -> Bw (fp32, 8 rows/chunk)
    const char* gsrc[4]; char* lbase[4]; int bstr[4], kst[4];
    #pragma unroll
    for (int j = 0; j < 4; ++j) {
        int c = w + j * 4;
        if (c < 8) {
            int rl = lane >> 2, sl = lane & 3;
            int row = c * 16 + rl;
            int pa = p0 + row; if (pa >= end) pa = end - 1;
            int f = (row & 3) ^ ((row >> 2) & 3);
            gsrc[j] = (const char*)(h + (size_t)pa * HH + ((sl ^ f) << 3));
            lbase[j] = (char*)&Ah[0][c * 16][0];
            bstr[j] = 128 * 32 * 2; kst[j] = 32 * 2;
        } else {
            int rl = lane >> 3, sl = lane & 7;
            int row = (c - 8) * 8 + rl;
            gsrc[j] = (const char*)(w2p + (size_t)(c0 + row) * HH + ((sl ^ (row & 7)) << 2));
            lbase[j] = (char*)&Bw[0][(c - 8) * 8][0];
            bstr[j] = 64 * 32 * 4; kst[j] = 32 * 4;
        }
    }

    const f4 z4 = {0.f, 0.f, 0.f, 0.f};
    f4 acc[2][4] = {{z4, z4, z4, z4}, {z4, z4, z4, z4}};
    const int sw = (quad ^ (l16 & 3) ^ (l16 >> 2)) * 8;
    const int fa = l16 & 7;
    const int ra0 = w * 32 + l16, ra1 = ra0 + 16;

    auto STAGE = [&](int buf, int kt) {
        #pragma unroll
        for (int j = 0; j < 4; ++j)
            gld16(gsrc[j] + (size_t)kt * kst[j], lbase[j] + (size_t)buf * bstr[j]);
    };
    auto COMPUTE = [&](int buf) {
        bfrag a0 = *(const bfrag*)&Ah[buf][ra0][sw];
        bfrag a1 = *(const bfrag*)&Ah[buf][ra1][sw];
        #pragma unroll
        for (int cb = 0; cb < 4; ++cb) {
            float fb[8];
            ldf8((const char*)&Bw[buf][cb * 16 + l16][0], fa, quad, fb);
            bfrag bb = cvt_hi8(fb);
            acc[0][cb] = MF(a0, bb, acc[0][cb]);
            acc[1][cb] = MF(a1, bb, acc[1][cb]);
        }
    };

    STAGE(0, 0);
    STAGE(1, 1);
    for (int kt = 0; kt < 16; ++kt) {
        if (kt < 15) asm volatile("s_waitcnt vmcnt(4)" ::: "memory");
        else         asm volatile("s_waitcnt vmcnt(0)" ::: "memory");
        __builtin_amdgcn_s_barrier();
        if (kt < 14) STAGE((kt + 2) % 3, kt + 2);
        COMPUTE(kt % 3);
    }

    const int pw0 = p0 + w * 32;
    float rs0[4] = {0.f, 0.f, 0.f, 0.f}, rs1[4] = {0.f, 0.f, 0.f, 0.f};
    #pragma unroll
    for (int i = 0; i < 4; ++i) {
        int row0i = quad * 4 + i, row1i = 16 + quad * 4 + i;
        int g0 = pw0 + row0i; if (g0 >= end) g0 = end - 1;
        int g1 = pw0 + row1i; if (g1 >= end) g1 = end - 1;
        int gr0 = brows[g0], gr1 = brows[g1];
        #pragma unroll
        for (int cb = 0; cb < 4; ++cb) {
            int col = c0 + cb * 16 + l16;
            float bias = eb2[e * H + col];
            float v0 = acc[0][cb][i] + bias;
            float v1 = acc[1][cb][i] + bias;
            vout[(size_t)gr0 * H + col] = v0;
            vout[(size_t)gr1 * H + col] = v1;
            rs0[i] += v0 * v0;
            rs1[i] += v1 * v1;
        }
    }
    #pragma unroll
    for (int i = 0; i < 4; ++i) {
        float s0 = rs0[i], s1 = rs1[i];
        #pragma unroll
        for (int off = 8; off; off >>= 1) {
            s0 += __shfl_xor(s0, off, 16);
            s1 += __shfl_xor(s1, off, 16);
        }
        if (l16 == 0) {
            int g0 = pw0 + quad * 4 + i;      if (g0 >= end) g0 = end - 1;
            int g1 = pw0 + 16 + quad * 4 + i; if (g1 >= end) g1 = end - 1;
            psum[(size_t)brows[g0] * 16 + cg] = s0;
            psum[(size_t)brows[g1] * 16 + cg] = s1;
        }
    }
}

// out = v * scale + q ; scale computed inline from psum (one block per row)
__global__ __launch_bounds__(256) void finalize_kernel(
    float* __restrict__ out, const float* __restrict__ q,
    const float* __restrict__ psum, const float* __restrict__ gval)
{
    const int row = blockIdx.x, t = threadIdx.x;
    float s = 0.f;
    #pragma unroll
    for (int j = 0; j < 16; ++j) s += psum[(size_t)row * 16 + j];
    float g = gval[row];
    float sc = g / fmaxf(g * sqrtf(s), 1e-6f);
    size_t i = (size_t)row * 256 + t;
    float4 v = ((const float4*)out)[i];
    float4 qq = ((const float4*)q)[i];
    float4 o;
    o.x = v.x * sc + qq.x;
    o.y = v.y * sc + qq.y;
    o.z = v.z * sc + qq.z;
    o.w = v.w * sc + qq.w;
    ((float4*)out)[i] = o;
}

extern "C" void kernel_launch(void* const* d_in, const int* in_sizes, int n_in,
                              void* d_out, int out_size, void* d_ws, size_t ws_size,
                              hipStream_t stream) {
    const float* q      = (const float*)d_in[0];
    const float* cls1_w = (const float*)d_in[1];
    const float* cls1_b = (const float*)d_in[2];
    const float* cls3_w = (const float*)d_in[3];
    const float* cls3_b = (const float*)d_in[4];
    const float* exp_w1 = (const float*)d_in[5];
    const float* exp_b1 = (const float*)d_in[6];
    const float* exp_w2 = (const float*)d_in[7];
    const float* exp_b2 = (const float*)d_in[8];
    float* out = (float*)d_out;

    // ---- workspace layout (~29 MB) ----
    char* w = (char*)d_ws;
    float* psum   = (float*)w;              w += (size_t)NB * 16 * 4;
    float* gvalp  = (float*)w;              w += (size_t)NB * 4;
    int* top1     = (int*)w;                w += (size_t)NB * 4;
    int* brows    = (int*)w;                w += (size_t)NB * 4;
    int* ambig_rows = (int*)w;              w += (size_t)NB * 4;
    int* counts   = (int*)w;                w += 16 * 4;
    int* ambig_cnt = (int*)w;               w += 4 * 4;
    int* tm_e     = (int*)w;                w += NT128 * 4;
    int* tm_p     = (int*)w;                w += NT128 * 4;
    int* tm_end   = (int*)w;                w += NT128 * 4;
    w = (char*)(((size_t)w + 15) & ~(size_t)15);
    unsigned short* x1hi = (unsigned short*)w;                              // dead after logits
    unsigned short* x1lo = x1hi + (size_t)NB * HH;  w += (size_t)NB * HH * 2 * 2;  // -> x1buf
    unsigned short* hbuf = (unsigned short*)w;  w += (size_t)NB * HH * 2;
    unsigned short* w1hi = (unsigned short*)w;  w += (size_t)HH * H * 2;
    unsigned short* w1lo = (unsigned short*)w;  w += (size_t)HH * H * 2;
    unsigned short* w3hi = (unsigned short*)w;  w += (size_t)NEXP * HH * 2;
    unsigned short* w3lo = (unsigned short*)w;  w += (size_t)NEXP * HH * 2;
    float* x1buf = (float*)x1hi;   // fp32 fixup scratch aliasing dead x1hi/x1lo

    cvtW_kernel<<<520, 256, 0, stream>>>(cls1_w, cls3_w, w1hi, w1lo, w3hi, w3lo,
                                         counts, ambig_cnt);
    g1_kernel<<<dim3(NB / 128, 8), 256, 0, stream>>>(q, w1hi, w1lo, cls1_b, x1hi, x1lo);
    logits_kernel<<<NB / 32, 256, 0, stream>>>(x1hi, x1lo, w3hi, w3lo, cls3_b,
                                               top1, gvalp, counts, ambig_rows, ambig_cnt);
    fixup1_kernel<<<256, 256, 0, stream>>>(q, cls1_w, cls1_b, ambig_rows, ambig_cnt, x1buf);
    fixup2_kernel<<<64, 256, 0, stream>>>(x1buf, cls3_w, cls3_b, ambig_rows, ambig_cnt,
                                          top1, gvalp, counts);
    osc_kernel<<<1, 256, 0, stream>>>(counts, tm_e, tm_p, tm_end, top1, brows);
    exp1_kernel<<<dim3(NT128, 8), 256, 0, stream>>>(q, exp_w1, exp_b1,
                                                    tm_e, tm_p, tm_end, brows, hbuf);
    exp2_kernel<<<dim3(NT128, 16), 256, 0, stream>>>(hbuf, exp_w2, exp_b2,
                                                     tm_e, tm_p, tm_end, brows, out, psum);
    finalize_kernel<<<NB, 256, 0, stream>>>(out, q, psum, gvalp);
}

// Round 6
// 371.731 us; speedup vs baseline: 1.1444x; 1.1444x over previous
//
#include <hip/hip_runtime.h>
#include <math.h>

#define NB 8192
#define H 1024
#define HH 512
#define NEXP 16
#define NT128 96            // max sum of per-expert ceil(cnt/128), padded
#define AMBIG_THR 1e-3f     // ~50 sigma of split-bf16 logit error

// MFMA 16x16x32 bf16 fragments
typedef __attribute__((ext_vector_type(8))) short bfrag;
typedef __attribute__((ext_vector_type(4))) float f4;

__device__ __forceinline__ f4 MF(bfrag a, bfrag b, f4 c) {
    return __builtin_amdgcn_mfma_f32_16x16x32_bf16(a, b, c, 0, 0, 0);
}
__device__ __forceinline__ unsigned short f2bf(float f) {  // RNE fp32->bf16
    unsigned u = __float_as_uint(f);
    u += 0x7fff + ((u >> 16) & 1);
    return (unsigned short)(u >> 16);
}
__device__ __forceinline__ float bf2f(unsigned short h) {
    return __uint_as_float((unsigned)h << 16);
}

// async global->LDS, 16B per lane; LDS dest is wave-uniform base + lane*16
typedef __attribute__((address_space(1))) const unsigned GAS;
typedef __attribute__((address_space(3))) unsigned LAS;
__device__ __forceinline__ void gld16(const void* g, void* l) {
    __builtin_amdgcn_global_load_lds((GAS*)g, (LAS*)l, 16, 0, 0);
}

// fused split-conversion: q (8192 blocks), w1 (512), w3 (8); block 0 zeroes counters
__global__ __launch_bounds__(256) void cvtA_kernel(
    const float* __restrict__ q, const float* __restrict__ w1, const float* __restrict__ w3,
    unsigned short* __restrict__ qhi, unsigned short* __restrict__ qlo,
    unsigned short* __restrict__ w1hi, unsigned short* __restrict__ w1lo,
    unsigned short* __restrict__ w3hi, unsigned short* __restrict__ w3lo,
    int* __restrict__ counts, int* __restrict__ ambig_cnt)
{
    const int b = blockIdx.x, t = threadIdx.x;
    if (b == 0) {
        if (t < NEXP) counts[t] = 0;
        if (t == NEXP) ambig_cnt[0] = 0;
    }
    const float* src; unsigned short *hi, *lo; int i;
    if (b < 8192)      { src = q;  hi = qhi;  lo = qlo;  i = b * 256 + t; }
    else if (b < 8704) { src = w1; hi = w1hi; lo = w1lo; i = (b - 8192) * 256 + t; }
    else               { src = w3; hi = w3hi; lo = w3lo; i = (b - 8704) * 256 + t; }
    float4 v = ((const float4*)src)[i];
    ushort4 h, l;
    h.x = f2bf(v.x); l.x = f2bf(v.x - bf2f(h.x));
    h.y = f2bf(v.y); l.y = f2bf(v.y - bf2f(h.y));
    h.z = f2bf(v.z); l.z = f2bf(v.z - bf2f(h.z));
    h.w = f2bf(v.w); l.w = f2bf(v.w - bf2f(h.w));
    ((ushort4*)hi)[i] = h;
    ((ushort4*)lo)[i] = l;
}

// fused plain conversion: exp_w1 (8192 blocks), exp_w2 (8192 blocks)
__global__ __launch_bounds__(256) void cvtB_kernel(
    const float* __restrict__ ew1, const float* __restrict__ ew2,
    unsigned short* __restrict__ d1, unsigned short* __restrict__ d2)
{
    const int b = blockIdx.x, t = threadIdx.x;
    const float* src; unsigned short* dst; int i;
    if (b < 8192) { src = ew1; dst = d1; i = b * 256 + t; }
    else          { src = ew2; dst = d2; i = (b - 8192) * 256 + t; }
    float4 v = ((const float4*)src)[i];
    ushort4 h;
    h.x = f2bf(v.x); h.y = f2bf(v.y); h.z = f2bf(v.z); h.w = f2bf(v.w);
    ((ushort4*)dst)[i] = h;
}

// ---- gating GEMM1 (split 3-term): x1 = relu(q @ w1^T + b1), stored hi/lo ----
// 64x64 tile (occupancy fix: grid 1024, LDS 48KB -> 3 blocks/CU = 12 waves/CU),
// 4 waves each 16 rows x 64 cols. Triple-buffered counted-vmcnt pipeline.
__global__ __launch_bounds__(256) void g1_kernel(
    const unsigned short* __restrict__ qhi, const unsigned short* __restrict__ qlo,
    const unsigned short* __restrict__ w1hi, const unsigned short* __restrict__ w1lo,
    const float* __restrict__ b1,
    unsigned short* __restrict__ x1hi, unsigned short* __restrict__ x1lo)
{
    __shared__ unsigned short Ah[3][64][32];
    __shared__ unsigned short Al[3][64][32];
    __shared__ unsigned short Bh[3][64][32];
    __shared__ unsigned short Bl[3][64][32];

    const int t = threadIdx.x, w = t >> 6, lane = t & 63;
    const int quad = lane >> 4, l16 = lane & 15;
    const int rowA0 = blockIdx.x * 64;
    const int colB0 = blockIdx.y * 64;
    const int rl = lane >> 2, sl = lane & 3;   // staging: 16 rows x 4 slots per 1KB chunk

    // 16 chunks/kt, 4 per wave: c 0-3 Ah, 4-7 Al, 8-11 Bh, 12-15 Bl (16 rows each)
    const unsigned short* gsrc[4];
    unsigned short* lbase[4];
    #pragma unroll
    for (int j = 0; j < 4; ++j) {
        int c = w + j * 4;
        int rloc; const unsigned short* s; unsigned short* d;
        if (c < 4)       { rloc = c * 16 + rl;        s = qhi  + (size_t)(rowA0 + rloc) * H; d = &Ah[0][c * 16][0]; }
        else if (c < 8)  { rloc = (c - 4) * 16 + rl;  s = qlo  + (size_t)(rowA0 + rloc) * H; d = &Al[0][(c - 4) * 16][0]; }
        else if (c < 12) { rloc = (c - 8) * 16 + rl;  s = w1hi + (size_t)(colB0 + rloc) * H; d = &Bh[0][(c - 8) * 16][0]; }
        else             { rloc = (c - 12) * 16 + rl; s = w1lo + (size_t)(colB0 + rloc) * H; d = &Bl[0][(c - 12) * 16][0]; }
        int f = (rloc & 3) ^ ((rloc >> 2) & 3);
        gsrc[j]  = s + (sl ^ f) * 8;   // pre-swizzled k-slot in the source
        lbase[j] = d;
    }
    const int bstr = 64 * 32;

    const f4 z4 = {0.f, 0.f, 0.f, 0.f};
    f4 acc[4] = {z4, z4, z4, z4};
    // read row = w*16 + l16: (row&3)^((row>>2)&3) = (l16&3)^(l16>>2) since w*16>>2 = 0 mod 4
    const int sw = (quad ^ (l16 & 3) ^ (l16 >> 2)) * 8;
    const int ra = w * 16 + l16;

    auto STAGE = [&](int buf, int kt) {
        #pragma unroll
        for (int j = 0; j < 4; ++j)
            gld16(gsrc[j] + kt * 32, lbase[j] + buf * bstr);
    };
    auto COMPUTE = [&](int buf) {
        bfrag ah = *(const bfrag*)&Ah[buf][ra][sw];
        bfrag al = *(const bfrag*)&Al[buf][ra][sw];
        #pragma unroll
        for (int cb = 0; cb < 4; ++cb) {
            bfrag bh = *(const bfrag*)&Bh[buf][cb * 16 + l16][sw];
            bfrag bl = *(const bfrag*)&Bl[buf][cb * 16 + l16][sw];
            acc[cb] = MF(al, bh, MF(ah, bl, MF(ah, bh, acc[cb])));
        }
    };

    STAGE(0, 0);
    STAGE(1, 1);
    for (int kt = 0; kt < 32; ++kt) {
        if (kt < 31) asm volatile("s_waitcnt vmcnt(4)" ::: "memory");
        else         asm volatile("s_waitcnt vmcnt(0)" ::: "memory");
        __builtin_amdgcn_s_barrier();
        if (kt < 30) STAGE((kt + 2) % 3, kt + 2);
        COMPUTE(kt % 3);
    }

    const int row0 = rowA0 + w * 16;
    #pragma unroll
    for (int cb = 0; cb < 4; ++cb) {
        int col = colB0 + cb * 16 + l16;
        float bias = b1[col];
        #pragma unroll
        for (int i = 0; i < 4; ++i) {
            int row = quad * 4 + i;
            float v = fmaxf(acc[cb][i] + bias, 0.f);
            unsigned short hh = f2bf(v);
            size_t idx = (size_t)(row0 + row) * HH + col;
            x1hi[idx] = hh;
            x1lo[idx] = f2bf(v - bf2f(hh));
        }
    }
}

// ---- logits (split 3-term) + argmax + gate + counts + ambiguity flag ----
__global__ __launch_bounds__(256) void logits_kernel(
    const unsigned short* __restrict__ x1hi, const unsigned short* __restrict__ x1lo,
    const unsigned short* __restrict__ w3hi, const unsigned short* __restrict__ w3lo,
    const float* __restrict__ b3,
    int* __restrict__ top1, float* __restrict__ gval, int* __restrict__ counts,
    int* __restrict__ ambig_rows, int* __restrict__ ambig_cnt)
{
    __shared__ float lgp[4][32][NEXP];
    const int t = threadIdx.x, wave = t >> 6, lane = t & 63;
    const int quad = lane >> 4, l16 = lane & 15;
    const int row0 = blockIdx.x * 32;
    const f4 z4 = {0.f, 0.f, 0.f, 0.f};

    f4 l0 = z4, l1 = z4;
    const size_t ar0 = (size_t)(row0 + l16) * HH + quad * 8;
    const size_t ar1 = ar0 + (size_t)16 * HH;
    const size_t br = (size_t)l16 * HH + quad * 8;
    #pragma unroll
    for (int ks = 0; ks < 4; ++ks) {
        int kk = wave * 128 + ks * 32;
        bfrag ah0 = *(const bfrag*)(x1hi + ar0 + kk);
        bfrag al0 = *(const bfrag*)(x1lo + ar0 + kk);
        bfrag ah1 = *(const bfrag*)(x1hi + ar1 + kk);
        bfrag al1 = *(const bfrag*)(x1lo + ar1 + kk);
        bfrag bh  = *(const bfrag*)(w3hi + br + kk);
        bfrag bl  = *(const bfrag*)(w3lo + br + kk);
        l0 = MF(al0, bh, MF(ah0, bl, MF(ah0, bh, l0)));
        l1 = MF(al1, bh, MF(ah1, bl, MF(ah1, bh, l1)));
    }
    #pragma unroll
    for (int i = 0; i < 4; ++i) {
        lgp[wave][quad * 4 + i][l16] = l0[i];
        lgp[wave][16 + quad * 4 + i][l16] = l1[i];
    }
    __syncthreads();

    if (t < 32) {
        float lg[NEXP];
        #pragma unroll
        for (int m = 0; m < NEXP; ++m)
            lg[m] = lgp[0][t][m] + lgp[1][t][m] + lgp[2][t][m] + lgp[3][t][m] + b3[m];
        float best = lg[0], second = -3.4e38f; int bi = 0;
        #pragma unroll
        for (int m = 1; m < NEXP; ++m) {
            float v = lg[m];
            if (v > best) { second = best; best = v; bi = m; }
            else if (v > second) second = v;
        }
        float se = 0.f;
        #pragma unroll
        for (int m = 0; m < NEXP; ++m) se += expf(lg[m] - best);
        int grow = row0 + t;
        top1[grow] = bi;
        gval[grow] = 1.f / se;
        atomicAdd(&counts[bi], 1);
        if (best - second < AMBIG_THR) {
            int pos = atomicAdd(ambig_cnt, 1);
            if (pos < NB) ambig_rows[pos] = grow;
        }
    }
}

// ---- exact fp32 x1 recompute for ambiguous rows, column-parallel ----
__global__ __launch_bounds__(256) void fixup1_kernel(
    const float* __restrict__ q, const float* __restrict__ w1, const float* __restrict__ b1,
    const int* __restrict__ ambig_rows, const int* __restrict__ ambig_cnt,
    float* __restrict__ x1buf)
{
    __shared__ __align__(16) float qrow[H];
    const int t = threadIdx.x, wv = t >> 6, ln = t & 63;
    const int chunk = blockIdx.x & 7;
    const int slot  = blockIdx.x >> 3;
    const int base  = chunk * 64;
    int nn = *ambig_cnt; if (nn > NB) nn = NB;
    for (int ii = slot; ii < nn; ii += 32) {
        int row = ambig_rows[ii];
        ((float4*)qrow)[t] = ((const float4*)(q + (size_t)row * H))[t];
        __syncthreads();
        for (int c = base + wv * 2; c < base + 64; c += 8) {
            const float4* w0 = (const float4*)(w1 + (size_t)c * H);
            const float4* w1r = (const float4*)(w1 + (size_t)(c + 1) * H);
            const float4* qv = (const float4*)qrow;
            float s0 = 0.f, s1 = 0.f;
            #pragma unroll
            for (int j = 0; j < 4; ++j) {
                float4 a = qv[j * 64 + ln];
                float4 b0 = w0[j * 64 + ln];
                float4 b1v = w1r[j * 64 + ln];
                s0 += a.x * b0.x + a.y * b0.y + a.z * b0.z + a.w * b0.w;
                s1 += a.x * b1v.x + a.y * b1v.y + a.z * b1v.z + a.w * b1v.w;
            }
            #pragma unroll
            for (int off = 32; off; off >>= 1) {
                s0 += __shfl_xor(s0, off, 64);
                s1 += __shfl_xor(s1, off, 64);
            }
            if (ln == 0) {
                x1buf[(size_t)ii * HH + c]     = fmaxf(s0 + b1[c], 0.f);
                x1buf[(size_t)ii * HH + c + 1] = fmaxf(s1 + b1[c + 1], 0.f);
            }
        }
        __syncthreads();
    }
}

// ---- logits from exact x1 + top1/gval/counts update ----
__global__ __launch_bounds__(256) void fixup2_kernel(
    const float* __restrict__ x1buf,
    const float* __restrict__ w3, const float* __restrict__ b3,
    const int* __restrict__ ambig_rows, const int* __restrict__ ambig_cnt,
    int* __restrict__ top1, float* __restrict__ gval, int* __restrict__ counts)
{
    __shared__ float lgs[NEXP];
    const int t = threadIdx.x, wv = t >> 6, ln = t & 63;
    int nn = *ambig_cnt; if (nn > NB) nn = NB;
    for (int ii = blockIdx.x; ii < nn; ii += gridDim.x) {
        int row = ambig_rows[ii];
        const float4* xv = (const float4*)(x1buf + (size_t)ii * HH);
        for (int m = wv; m < NEXP; m += 4) {
            const float4* wr = (const float4*)(w3 + (size_t)m * HH);
            float s = 0.f;
            #pragma unroll
            for (int j = 0; j < 2; ++j) {
                float4 a = xv[j * 64 + ln];
                float4 b = wr[j * 64 + ln];
                s += a.x * b.x + a.y * b.y + a.z * b.z + a.w * b.w;
            }
            #pragma unroll
            for (int off = 32; off; off >>= 1) s += __shfl_xor(s, off, 64);
            if (ln == 0) lgs[m] = s + b3[m];
        }
        __syncthreads();
        if (t == 0) {
            float best = lgs[0]; int bi = 0;
            #pragma unroll
            for (int m = 1; m < NEXP; ++m) if (lgs[m] > best) { best = lgs[m]; bi = m; }
            float se = 0.f;
            #pragma unroll
            for (int m = 0; m < NEXP; ++m) se += expf(lgs[m] - best);
            int old = top1[row];
            if (bi != old) {
                atomicSub(&counts[old], 1);
                atomicAdd(&counts[bi], 1);
                top1[row] = bi;
            }
            gval[row] = 1.f / se;
        }
        __syncthreads();
    }
}

// fused offsets + tile-map + scatter (single block; LDS atomics)
__global__ __launch_bounds__(256) void osc_kernel(
    const int* __restrict__ counts,
    int* __restrict__ tm_e, int* __restrict__ tm_p, int* __restrict__ tm_end,
    const int* __restrict__ top1, int* __restrict__ brows)
{
    __shared__ int sbpos[NEXP];
    const int t = threadIdx.x;
    if (t == 0) {
        int run = 0, tile = 0;
        for (int e = 0; e < NEXP; ++e) {
            sbpos[e] = run;
            int beg = run, end = run + counts[e];
            for (int p = beg; p < end; p += 128) {
                tm_e[tile] = e; tm_p[tile] = p; tm_end[tile] = end; ++tile;
            }
            run = end;
        }
        for (; tile < NT128; ++tile) tm_e[tile] = -1;
    }
    __syncthreads();
    for (int i = t; i < NB; i += 256) {
        int e = top1[i];
        int pos = atomicAdd(&sbpos[e], 1);
        brows[pos] = i;
    }
}

// ---- expert GEMM1: h[pos][512] = relu(q[brows[pos]] @ w1[e]^T + b1[e]) ----
// Triple-buffered counted-vmcnt; 128x64 tile, BK=32, 4 waves. grid (NT128, 8).
__global__ __launch_bounds__(256) void exp1_kernel(
    const unsigned short* __restrict__ qb, const unsigned short* __restrict__ ew1b,
    const float* __restrict__ eb1,
    const int* __restrict__ tm_e, const int* __restrict__ tm_p, const int* __restrict__ tm_end,
    const int* __restrict__ brows, unsigned short* __restrict__ h)
{
    const int e = tm_e[blockIdx.x];
    if (e < 0) return;                       // block-uniform: safe with barriers
    const int p0 = tm_p[blockIdx.x], end = tm_end[blockIdx.x];

    __shared__ unsigned short A[3][128][32];
    __shared__ unsigned short B[3][64][32];

    const int t = threadIdx.x, w = t >> 6, lane = t & 63;
    const int quad = lane >> 4, l16 = lane & 15;
    const int c0 = blockIdx.y * 64;
    const unsigned short* w1p = ew1b + (size_t)e * HH * H;
    const int rl = lane >> 2, sl = lane & 3;

    const unsigned short* gsrc[3];
    unsigned short* lbase[3];
    int bstr[3];
    #pragma unroll
    for (int j = 0; j < 3; ++j) {
        int c = w + j * 4;
        int rloc; const unsigned short* s; unsigned short* d; int str;
        if (c < 8) {
            rloc = c * 16 + rl;
            int pa = p0 + rloc; if (pa >= end) pa = end - 1;   // ragged tail: duplicate last row
            s = qb + (size_t)brows[pa] * H;
            d = &A[0][c * 16][0]; str = 128 * 32;
        } else {
            rloc = (c - 8) * 16 + rl;
            s = w1p + (size_t)(c0 + rloc) * H;
            d = &B[0][(c - 8) * 16][0]; str = 64 * 32;
        }
        int f = (rloc & 3) ^ ((rloc >> 2) & 3);
        gsrc[j]  = s + (sl ^ f) * 8;
        lbase[j] = d;
        bstr[j]  = str;
    }

    const f4 z4 = {0.f, 0.f, 0.f, 0.f};
    f4 acc[2][4] = {{z4, z4, z4, z4}, {z4, z4, z4, z4}};
    const int sw = (quad ^ (l16 & 3) ^ (l16 >> 2)) * 8;
    const int ra0 = w * 32 + l16, ra1 = ra0 + 16;

    auto STAGE = [&](int buf, int kt) {
        #pragma unroll
        for (int j = 0; j < 3; ++j)
            gld16(gsrc[j] + kt * 32, lbase[j] + buf * bstr[j]);
    };
    auto COMPUTE = [&](int buf) {
        bfrag a0 = *(const bfrag*)&A[buf][ra0][sw];
        bfrag a1 = *(const bfrag*)&A[buf][ra1][sw];
        #pragma unroll
        for (int cb = 0; cb < 4; ++cb) {
            bfrag bb = *(const bfrag*)&B[buf][cb * 16 + l16][sw];
            acc[0][cb] = MF(a0, bb, acc[0][cb]);
            acc[1][cb] = MF(a1, bb, acc[1][cb]);
        }
    };

    STAGE(0, 0);
    STAGE(1, 1);
    for (int kt = 0; kt < 32; ++kt) {
        if (kt < 31) asm volatile("s_waitcnt vmcnt(3)" ::: "memory");
        else         asm volatile("s_waitcnt vmcnt(0)" ::: "memory");
        __builtin_amdgcn_s_barrier();
        if (kt < 30) STAGE((kt + 2) % 3, kt + 2);
        COMPUTE(kt % 3);
    }

    const int prow0 = p0 + w * 32;
    #pragma unroll
    for (int cb = 0; cb < 4; ++cb) {
        int col = c0 + cb * 16 + l16;
        float bias = eb1[e * HH + col];
        #pragma unroll
        for (int rb = 0; rb < 2; ++rb)
            #pragma unroll
            for (int i = 0; i < 4; ++i) {
                int row = rb * 16 + quad * 4 + i;
                if (prow0 + row < end)
                    h[(size_t)(prow0 + row) * HH + col] = f2bf(fmaxf(acc[rb][cb][i] + bias, 0.f));
            }
    }
}

// ---- expert GEMM2: v = h @ w2[e]^T + b2[e]; psum[row][cg] = partial sum v^2 ----
// Triple-buffered counted-vmcnt; 128x64 tile, BK=32, 4 waves. grid (NT128, 16).
__global__ __launch_bounds__(256) void exp2_kernel(
    const unsigned short* __restrict__ h, const unsigned short* __restrict__ ew2b,
    const float* __restrict__ eb2,
    const int* __restrict__ tm_e, const int* __restrict__ tm_p, const int* __restrict__ tm_end,
    const int* __restrict__ brows,
    float* __restrict__ vout, float* __restrict__ psum)
{
    const int e = tm_e[blockIdx.x];
    if (e < 0) return;
    const int p0 = tm_p[blockIdx.x], end = tm_end[blockIdx.x];

    __shared__ unsigned short A[3][128][32];
    __shared__ unsigned short B[3][64][32];

    const int t = threadIdx.x, w = t >> 6, lane = t & 63;
    const int quad = lane >> 4, l16 = lane & 15;
    const int cg = blockIdx.y;
    const int c0 = cg * 64;
    const unsigned short* w2p = ew2b + (size_t)e * H * HH;
    const int rl = lane >> 2, sl = lane & 3;

    const unsigned short* gsrc[3];
    unsigned short* lbase[3];
    int bstr[3];
    #pragma unroll
    for (int j = 0; j < 3; ++j) {
        int c = w + j * 4;
        int rloc; const unsigned short* s; unsigned short* d; int str;
        if (c < 8) {
            rloc = c * 16 + rl;
            int pa = p0 + rloc; if (pa >= end) pa = end - 1;
            s = h + (size_t)pa * HH;
            d = &A[0][c * 16][0]; str = 128 * 32;
        } else {
            rloc = (c - 8) * 16 + rl;
            s = w2p + (size_t)(c0 + rloc) * HH;
            d = &B[0][(c - 8) * 16][0]; str = 64 * 32;
        }
        int f = (rloc & 3) ^ ((rloc >> 2) & 3);
        gsrc[j]  = s + (sl ^ f) * 8;
        lbase[j] = d;
        bstr[j]  = str;
    }

    const f4 z4 = {0.f, 0.f, 0.f, 0.f};
    f4 acc[2][4] = {{z4, z4, z4, z4}, {z4, z4, z4, z4}};
    const int sw = (quad ^ (l16 & 3) ^ (l16 >> 2)) * 8;
    const int ra0 = w * 32 + l16, ra1 = ra0 + 16;

    auto STAGE = [&](int buf, int kt) {
        #pragma unroll
        for (int j = 0; j < 3; ++j)
            gld16(gsrc[j] + kt * 32, lbase[j] + buf * bstr[j]);
    };
    auto COMPUTE = [&](int buf) {
        bfrag a0 = *(const bfrag*)&A[buf][ra0][sw];
        bfrag a1 = *(const bfrag*)&A[buf][ra1][sw];
        #pragma unroll
        for (int cb = 0; cb < 4; ++cb) {
            bfrag bb = *(const bfrag*)&B[buf][cb * 16 + l16][sw];
            acc[0][cb] = MF(a0, bb, acc[0][cb]);
            acc[1][cb] = MF(a1, bb, acc[1][cb]);
        }
    };

    STAGE(0, 0);
    STAGE(1, 1);
    for (int kt = 0; kt < 16; ++kt) {
        if (kt < 15) asm volatile("s_waitcnt vmcnt(3)" ::: "memory");
        else         asm volatile("s_waitcnt vmcnt(0)" ::: "memory");
        __builtin_amdgcn_s_barrier();
        if (kt < 14) STAGE((kt + 2) % 3, kt + 2);
        COMPUTE(kt % 3);
    }

    // bias + v-write + per-row sum(v^2); wave w owns positions p0+w*32 .. +31
    const int pw0 = p0 + w * 32;
    float rs0[4] = {0.f, 0.f, 0.f, 0.f}, rs1[4] = {0.f, 0.f, 0.f, 0.f};
    #pragma unroll
    for (int i = 0; i < 4; ++i) {
        int row0i = quad * 4 + i, row1i = 16 + quad * 4 + i;
        int g0 = pw0 + row0i; if (g0 >= end) g0 = end - 1;
        int g1 = pw0 + row1i; if (g1 >= end) g1 = end - 1;
        int gr0 = brows[g0], gr1 = brows[g1];
        #pragma unroll
        for (int cb = 0; cb < 4; ++cb) {
            int col = c0 + cb * 16 + l16;
            float bias = eb2[e * H + col];
            float v0 = acc[0][cb][i] + bias;
            float v1 = acc[1][cb][i] + bias;
            vout[(size_t)gr0 * H + col] = v0;
            vout[(size_t)gr1 * H + col] = v1;
            rs0[i] += v0 * v0;
            rs1[i] += v1 * v1;
        }
    }
    #pragma unroll
    for (int i = 0; i < 4; ++i) {
        float s0 = rs0[i], s1 = rs1[i];
        #pragma unroll
        for (int off = 8; off; off >>= 1) {
            s0 += __shfl_xor(s0, off, 16);
            s1 += __shfl_xor(s1, off, 16);
        }
        if (l16 == 0) {
            int g0 = pw0 + quad * 4 + i;      if (g0 >= end) g0 = end - 1;
            int g1 = pw0 + 16 + quad * 4 + i; if (g1 >= end) g1 = end - 1;
            psum[(size_t)brows[g0] * 16 + cg] = s0;
            psum[(size_t)brows[g1] * 16 + cg] = s1;
        }
    }
}

// out = v * scale + q ; scale computed inline from psum (one block per row)
__global__ __launch_bounds__(256) void finalize_kernel(
    float* __restrict__ out, const float* __restrict__ q,
    const float* __restrict__ psum, const float* __restrict__ gval)
{
    const int row = blockIdx.x, t = threadIdx.x;
    float s = 0.f;
    #pragma unroll
    for (int j = 0; j < 16; ++j) s += psum[(size_t)row * 16 + j];
    float g = gval[row];
    float sc = g / fmaxf(g * sqrtf(s), 1e-6f);
    size_t i = (size_t)row * 256 + t;
    float4 v = ((const float4*)out)[i];
    float4 qq = ((const float4*)q)[i];
    float4 o;
    o.x = v.x * sc + qq.x;
    o.y = v.y * sc + qq.y;
    o.z = v.z * sc + qq.z;
    o.w = v.w * sc + qq.w;
    ((float4*)out)[i] = o;
}

extern "C" void kernel_launch(void* const* d_in, const int* in_sizes, int n_in,
                              void* d_out, int out_size, void* d_ws, size_t ws_size,
                              hipStream_t stream) {
    const float* q      = (const float*)d_in[0];
    const float* cls1_w = (const float*)d_in[1];
    const float* cls1_b = (const float*)d_in[2];
    const float* cls3_w = (const float*)d_in[3];
    const float* cls3_b = (const float*)d_in[4];
    const float* exp_w1 = (const float*)d_in[5];
    const float* exp_b1 = (const float*)d_in[6];
    const float* exp_w2 = (const float*)d_in[7];
    const float* exp_b2 = (const float*)d_in[8];
    float* out = (float*)d_out;

    // ---- workspace layout (~62 MB), lifetime-based aliasing ----
    char* w = (char*)d_ws;
    float* psum   = (float*)w;              w += (size_t)NB * 16 * 4;
    float* gvalp  = (float*)w;              w += (size_t)NB * 4;
    int* top1     = (int*)w;                w += (size_t)NB * 4;
    int* brows    = (int*)w;                w += (size_t)NB * 4;
    int* ambig_rows = (int*)w;              w += (size_t)NB * 4;
    int* counts   = (int*)w;                w += 16 * 4;
    int* ambig_cnt = (int*)w;               w += 4 * 4;
    int* tm_e     = (int*)w;                w += NT128 * 4;
    int* tm_p     = (int*)w;                w += NT128 * 4;
    int* tm_end   = (int*)w;                w += NT128 * 4;
    w = (char*)(((size_t)w + 15) & ~(size_t)15);
    unsigned short* qhi  = (unsigned short*)w;  w += (size_t)NB * H * 2;   // lives whole pipeline
    unsigned short* qlo  = (unsigned short*)w;  w += (size_t)NB * H * 2;   // dead after g1 -> ew2b
    unsigned short* x1hi = (unsigned short*)w;                              // dead after logits
    unsigned short* x1lo = x1hi + (size_t)NB * HH;  w += (size_t)NB * HH * 2 * 2;  // -> x1buf -> ew1b
    unsigned short* hbuf = (unsigned short*)w;  w += (size_t)NB * HH * 2;
    unsigned short* w1hi = (unsigned short*)w;  w += (size_t)HH * H * 2;
    unsigned short* w1lo = (unsigned short*)w;  w += (size_t)HH * H * 2;
    unsigned short* w3hi = (unsigned short*)w;  w += (size_t)NEXP * HH * 2;
    unsigned short* w3lo = (unsigned short*)w;  w += (size_t)NEXP * HH * 2;
    unsigned short* ew1b = x1hi;   // reused after logits+fixup
    unsigned short* ew2b = qlo;    // reused after g1
    float* x1buf = (float*)x1hi;   // fp32 fixup scratch aliasing dead x1hi/x1lo

    cvtA_kernel<<<8712, 256, 0, stream>>>(q, cls1_w, cls3_w, qhi, qlo, w1hi, w1lo,
                                          w3hi, w3lo, counts, ambig_cnt);
    g1_kernel<<<dim3(NB / 64, 8), 256, 0, stream>>>(qhi, qlo, w1hi, w1lo, cls1_b, x1hi, x1lo);
    logits_kernel<<<NB / 32, 256, 0, stream>>>(x1hi, x1lo, w3hi, w3lo, cls3_b,
                                               top1, gvalp, counts, ambig_rows, ambig_cnt);
    fixup1_kernel<<<256, 256, 0, stream>>>(q, cls1_w, cls1_b, ambig_rows, ambig_cnt, x1buf);
    fixup2_kernel<<<64, 256, 0, stream>>>(x1buf, cls3_w, cls3_b, ambig_rows, ambig_cnt,
                                          top1, gvalp, counts);
    cvtB_kernel<<<16384, 256, 0, stream>>>(exp_w1, exp_w2, ew1b, ew2b);
    osc_kernel<<<1, 256, 0, stream>>>(counts, tm_e, tm_p, tm_end, top1, brows);
    exp1_kernel<<<dim3(NT128, 8), 256, 0, stream>>>(qhi, ew1b, exp_b1,
                                                    tm_e, tm_p, tm_end, brows, hbuf);
    exp2_kernel<<<dim3(NT128, 16), 256, 0, stream>>>(hbuf, ew2b, exp_b2,
                                                     tm_e, tm_p, tm_end, brows, out, psum);
    finalize_kernel<<<NB, 256, 0, stream>>>(out, q, psum, gvalp);
}

// Round 7
// 359.047 us; speedup vs baseline: 1.1848x; 1.0353x over previous
//
#include <hip/hip_runtime.h>
#include <math.h>

#define NB 8192
#define H 1024
#define HH 512
#define NEXP 16
#define NT128 96            // max sum of per-expert ceil(cnt/128), padded
#define AMBIG_THR 1e-3f     // ~50 sigma of split-bf16 logit error

// MFMA 16x16x32 bf16 fragments
typedef __attribute__((ext_vector_type(8))) short bfrag;
typedef __attribute__((ext_vector_type(4))) float f4;

__device__ __forceinline__ f4 MF(bfrag a, bfrag b, f4 c) {
    return __builtin_amdgcn_mfma_f32_16x16x32_bf16(a, b, c, 0, 0, 0);
}
__device__ __forceinline__ unsigned short f2bf(float f) {  // RNE fp32->bf16
    unsigned u = __float_as_uint(f);
    u += 0x7fff + ((u >> 16) & 1);
    return (unsigned short)(u >> 16);
}
__device__ __forceinline__ float bf2f(unsigned short h) {
    return __uint_as_float((unsigned)h << 16);
}

// async global->LDS, 16B per lane; LDS dest is wave-uniform base + lane*16
typedef __attribute__((address_space(1))) const unsigned GAS;
typedef __attribute__((address_space(3))) unsigned LAS;
__device__ __forceinline__ void gld16(const void* g, void* l) {
    __builtin_amdgcn_global_load_lds((GAS*)g, (LAS*)l, 16, 0, 0);
}

// fused split-conversion: q (8192 blocks), w1 (512), w3 (8); block 0 zeroes counters
__global__ __launch_bounds__(256) void cvtA_kernel(
    const float* __restrict__ q, const float* __restrict__ w1, const float* __restrict__ w3,
    unsigned short* __restrict__ qhi, unsigned short* __restrict__ qlo,
    unsigned short* __restrict__ w1hi, unsigned short* __restrict__ w1lo,
    unsigned short* __restrict__ w3hi, unsigned short* __restrict__ w3lo,
    int* __restrict__ counts, int* __restrict__ ambig_cnt)
{
    const int b = blockIdx.x, t = threadIdx.x;
    if (b == 0) {
        if (t < NEXP) counts[t] = 0;
        if (t == NEXP) ambig_cnt[0] = 0;
    }
    const float* src; unsigned short *hi, *lo; int i;
    if (b < 8192)      { src = q;  hi = qhi;  lo = qlo;  i = b * 256 + t; }
    else if (b < 8704) { src = w1; hi = w1hi; lo = w1lo; i = (b - 8192) * 256 + t; }
    else               { src = w3; hi = w3hi; lo = w3lo; i = (b - 8704) * 256 + t; }
    float4 v = ((const float4*)src)[i];
    ushort4 h, l;
    h.x = f2bf(v.x); l.x = f2bf(v.x - bf2f(h.x));
    h.y = f2bf(v.y); l.y = f2bf(v.y - bf2f(h.y));
    h.z = f2bf(v.z); l.z = f2bf(v.z - bf2f(h.z));
    h.w = f2bf(v.w); l.w = f2bf(v.w - bf2f(h.w));
    ((ushort4*)hi)[i] = h;
    ((ushort4*)lo)[i] = l;
}

// fused plain conversion: exp_w1 (8192 blocks), exp_w2 (8192 blocks)
__global__ __launch_bounds__(256) void cvtB_kernel(
    const float* __restrict__ ew1, const float* __restrict__ ew2,
    unsigned short* __restrict__ d1, unsigned short* __restrict__ d2)
{
    const int b = blockIdx.x, t = threadIdx.x;
    const float* src; unsigned short* dst; int i;
    if (b < 8192) { src = ew1; dst = d1; i = b * 256 + t; }
    else          { src = ew2; dst = d2; i = (b - 8192) * 256 + t; }
    float4 v = ((const float4*)src)[i];
    ushort4 h;
    h.x = f2bf(v.x); h.y = f2bf(v.y); h.z = f2bf(v.z); h.w = f2bf(v.w);
    ((ushort4*)dst)[i] = h;
}

// ---- gating GEMM1 (split 3-term): x1 = relu(q @ w1^T + b1), stored hi/lo ----
// 128x128 tile (staged-bytes fix: A re-read 4x not 8x, B 64x): grid (64,4),
// 8 waves (512 thr) each 32x64 sub-tile, 3-buf LDS 96KB, counted vmcnt(4).
__global__ __launch_bounds__(512) void g1_kernel(
    const unsigned short* __restrict__ qhi, const unsigned short* __restrict__ qlo,
    const unsigned short* __restrict__ w1hi, const unsigned short* __restrict__ w1lo,
    const float* __restrict__ b1,
    unsigned short* __restrict__ x1hi, unsigned short* __restrict__ x1lo)
{
    __shared__ unsigned short Ah[3][128][32];
    __shared__ unsigned short Al[3][128][32];
    __shared__ unsigned short Bh[3][128][32];
    __shared__ unsigned short Bl[3][128][32];

    const int t = threadIdx.x, w = t >> 6, lane = t & 63;
    const int quad = lane >> 4, l16 = lane & 15;
    const int wr = w & 3, wc = w >> 2;          // 4 row-groups x 2 col-groups
    const int rowA0 = blockIdx.x * 128;
    const int colB0 = blockIdx.y * 128;
    const int rl = lane >> 2, sl = lane & 3;    // staging: 16 rows x 4 slots per 1KB chunk

    // 32 chunks/kt, 4 per wave: c 0-7 Ah, 8-15 Al, 16-23 Bh, 24-31 Bl (16 rows each)
    const unsigned short* gsrc[4];
    unsigned short* lbase[4];
    #pragma unroll
    for (int j = 0; j < 4; ++j) {
        int c = w + j * 8;
        int rloc; const unsigned short* s; unsigned short* d;
        if (c < 8)       { rloc = c * 16 + rl;        s = qhi  + (size_t)(rowA0 + rloc) * H; d = &Ah[0][c * 16][0]; }
        else if (c < 16) { rloc = (c - 8) * 16 + rl;  s = qlo  + (size_t)(rowA0 + rloc) * H; d = &Al[0][(c - 8) * 16][0]; }
        else if (c < 24) { rloc = (c - 16) * 16 + rl; s = w1hi + (size_t)(colB0 + rloc) * H; d = &Bh[0][(c - 16) * 16][0]; }
        else             { rloc = (c - 24) * 16 + rl; s = w1lo + (size_t)(colB0 + rloc) * H; d = &Bl[0][(c - 24) * 16][0]; }
        int f = (rloc & 3) ^ ((rloc >> 2) & 3);
        gsrc[j]  = s + (sl ^ f) * 8;   // pre-swizzled k-slot in the source
        lbase[j] = d;
    }
    const int bstr = 128 * 32;

    const f4 z4 = {0.f, 0.f, 0.f, 0.f};
    f4 acc[2][4] = {{z4, z4, z4, z4}, {z4, z4, z4, z4}};
    // read rows: A = wr*32 + l16 (+16), B = wc*64 + cb*16 + l16; offsets vanish mod XOR masks
    const int sw = (quad ^ (l16 & 3) ^ (l16 >> 2)) * 8;
    const int ra0 = wr * 32 + l16, ra1 = ra0 + 16;
    const int cbase = wc * 64;

    auto STAGE = [&](int buf, int kt) {
        #pragma unroll
        for (int j = 0; j < 4; ++j)
            gld16(gsrc[j] + kt * 32, lbase[j] + buf * bstr);
    };
    auto COMPUTE = [&](int buf) {
        bfrag ah0 = *(const bfrag*)&Ah[buf][ra0][sw];
        bfrag al0 = *(const bfrag*)&Al[buf][ra0][sw];
        bfrag ah1 = *(const bfrag*)&Ah[buf][ra1][sw];
        bfrag al1 = *(const bfrag*)&Al[buf][ra1][sw];
        #pragma unroll
        for (int cb = 0; cb < 4; ++cb) {
            bfrag bh = *(const bfrag*)&Bh[buf][cbase + cb * 16 + l16][sw];
            bfrag bl = *(const bfrag*)&Bl[buf][cbase + cb * 16 + l16][sw];
            acc[0][cb] = MF(al0, bh, MF(ah0, bl, MF(ah0, bh, acc[0][cb])));
            acc[1][cb] = MF(al1, bh, MF(ah1, bl, MF(ah1, bh, acc[1][cb])));
        }
    };

    STAGE(0, 0);
    STAGE(1, 1);
    for (int kt = 0; kt < 32; ++kt) {
        if (kt < 31) asm volatile("s_waitcnt vmcnt(4)" ::: "memory");
        else         asm volatile("s_waitcnt vmcnt(0)" ::: "memory");
        __builtin_amdgcn_s_barrier();
        if (kt < 30) STAGE((kt + 2) % 3, kt + 2);
        COMPUTE(kt % 3);
    }

    const int row0 = rowA0 + wr * 32;
    #pragma unroll
    for (int cb = 0; cb < 4; ++cb) {
        int col = colB0 + cbase + cb * 16 + l16;
        float bias = b1[col];
        #pragma unroll
        for (int rb = 0; rb < 2; ++rb)
            #pragma unroll
            for (int i = 0; i < 4; ++i) {
                int row = rb * 16 + quad * 4 + i;
                float v = fmaxf(acc[rb][cb][i] + bias, 0.f);
                unsigned short hh = f2bf(v);
                size_t idx = (size_t)(row0 + row) * HH + col;
                x1hi[idx] = hh;
                x1lo[idx] = f2bf(v - bf2f(hh));
            }
    }
}

// ---- logits (split 3-term) + argmax + gate + counts + ambiguity flag ----
__global__ __launch_bounds__(256) void logits_kernel(
    const unsigned short* __restrict__ x1hi, const unsigned short* __restrict__ x1lo,
    const unsigned short* __restrict__ w3hi, const unsigned short* __restrict__ w3lo,
    const float* __restrict__ b3,
    int* __restrict__ top1, float* __restrict__ gval, int* __restrict__ counts,
    int* __restrict__ ambig_rows, int* __restrict__ ambig_cnt)
{
    __shared__ float lgp[4][32][NEXP];
    const int t = threadIdx.x, wave = t >> 6, lane = t & 63;
    const int quad = lane >> 4, l16 = lane & 15;
    const int row0 = blockIdx.x * 32;
    const f4 z4 = {0.f, 0.f, 0.f, 0.f};

    f4 l0 = z4, l1 = z4;
    const size_t ar0 = (size_t)(row0 + l16) * HH + quad * 8;
    const size_t ar1 = ar0 + (size_t)16 * HH;
    const size_t br = (size_t)l16 * HH + quad * 8;
    #pragma unroll
    for (int ks = 0; ks < 4; ++ks) {
        int kk = wave * 128 + ks * 32;
        bfrag ah0 = *(const bfrag*)(x1hi + ar0 + kk);
        bfrag al0 = *(const bfrag*)(x1lo + ar0 + kk);
        bfrag ah1 = *(const bfrag*)(x1hi + ar1 + kk);
        bfrag al1 = *(const bfrag*)(x1lo + ar1 + kk);
        bfrag bh  = *(const bfrag*)(w3hi + br + kk);
        bfrag bl  = *(const bfrag*)(w3lo + br + kk);
        l0 = MF(al0, bh, MF(ah0, bl, MF(ah0, bh, l0)));
        l1 = MF(al1, bh, MF(ah1, bl, MF(ah1, bh, l1)));
    }
    #pragma unroll
    for (int i = 0; i < 4; ++i) {
        lgp[wave][quad * 4 + i][l16] = l0[i];
        lgp[wave][16 + quad * 4 + i][l16] = l1[i];
    }
    __syncthreads();

    if (t < 32) {
        float lg[NEXP];
        #pragma unroll
        for (int m = 0; m < NEXP; ++m)
            lg[m] = lgp[0][t][m] + lgp[1][t][m] + lgp[2][t][m] + lgp[3][t][m] + b3[m];
        float best = lg[0], second = -3.4e38f; int bi = 0;
        #pragma unroll
        for (int m = 1; m < NEXP; ++m) {
            float v = lg[m];
            if (v > best) { second = best; best = v; bi = m; }
            else if (v > second) second = v;
        }
        float se = 0.f;
        #pragma unroll
        for (int m = 0; m < NEXP; ++m) se += expf(lg[m] - best);
        int grow = row0 + t;
        top1[grow] = bi;
        gval[grow] = 1.f / se;
        atomicAdd(&counts[bi], 1);
        if (best - second < AMBIG_THR) {
            int pos = atomicAdd(ambig_cnt, 1);
            if (pos < NB) ambig_rows[pos] = grow;
        }
    }
}

// ---- exact fp32 x1 recompute for ambiguous rows, column-parallel ----
__global__ __launch_bounds__(256) void fixup1_kernel(
    const float* __restrict__ q, const float* __restrict__ w1, const float* __restrict__ b1,
    const int* __restrict__ ambig_rows, const int* __restrict__ ambig_cnt,
    float* __restrict__ x1buf)
{
    __shared__ __align__(16) float qrow[H];
    const int t = threadIdx.x, wv = t >> 6, ln = t & 63;
    const int chunk = blockIdx.x & 7;
    const int slot  = blockIdx.x >> 3;
    const int base  = chunk * 64;
    int nn = *ambig_cnt; if (nn > NB) nn = NB;
    for (int ii = slot; ii < nn; ii += 32) {
        int row = ambig_rows[ii];
        ((float4*)qrow)[t] = ((const float4*)(q + (size_t)row * H))[t];
        __syncthreads();
        for (int c = base + wv * 2; c < base + 64; c += 8) {
            const float4* w0 = (const float4*)(w1 + (size_t)c * H);
            const float4* w1r = (const float4*)(w1 + (size_t)(c + 1) * H);
            const float4* qv = (const float4*)qrow;
            float s0 = 0.f, s1 = 0.f;
            #pragma unroll
            for (int j = 0; j < 4; ++j) {
                float4 a = qv[j * 64 + ln];
                float4 b0 = w0[j * 64 + ln];
                float4 b1v = w1r[j * 64 + ln];
                s0 += a.x * b0.x + a.y * b0.y + a.z * b0.z + a.w * b0.w;
                s1 += a.x * b1v.x + a.y * b1v.y + a.z * b1v.z + a.w * b1v.w;
            }
            #pragma unroll
            for (int off = 32; off; off >>= 1) {
                s0 += __shfl_xor(s0, off, 64);
                s1 += __shfl_xor(s1, off, 64);
            }
            if (ln == 0) {
                x1buf[(size_t)ii * HH + c]     = fmaxf(s0 + b1[c], 0.f);
                x1buf[(size_t)ii * HH + c + 1] = fmaxf(s1 + b1[c + 1], 0.f);
            }
        }
        __syncthreads();
    }
}

// ---- logits from exact x1 + top1/gval/counts update ----
__global__ __launch_bounds__(256) void fixup2_kernel(
    const float* __restrict__ x1buf,
    const float* __restrict__ w3, const float* __restrict__ b3,
    const int* __restrict__ ambig_rows, const int* __restrict__ ambig_cnt,
    int* __restrict__ top1, float* __restrict__ gval, int* __restrict__ counts)
{
    __shared__ float lgs[NEXP];
    const int t = threadIdx.x, wv = t >> 6, ln = t & 63;
    int nn = *ambig_cnt; if (nn > NB) nn = NB;
    for (int ii = blockIdx.x; ii < nn; ii += gridDim.x) {
        int row = ambig_rows[ii];
        const float4* xv = (const float4*)(x1buf + (size_t)ii * HH);
        for (int m = wv; m < NEXP; m += 4) {
            const float4* wr = (const float4*)(w3 + (size_t)m * HH);
            float s = 0.f;
            #pragma unroll
            for (int j = 0; j < 2; ++j) {
                float4 a = xv[j * 64 + ln];
                float4 b = wr[j * 64 + ln];
                s += a.x * b.x + a.y * b.y + a.z * b.z + a.w * b.w;
            }
            #pragma unroll
            for (int off = 32; off; off >>= 1) s += __shfl_xor(s, off, 64);
            if (ln == 0) lgs[m] = s + b3[m];
        }
        __syncthreads();
        if (t == 0) {
            float best = lgs[0]; int bi = 0;
            #pragma unroll
            for (int m = 1; m < NEXP; ++m) if (lgs[m] > best) { best = lgs[m]; bi = m; }
            float se = 0.f;
            #pragma unroll
            for (int m = 0; m < NEXP; ++m) se += expf(lgs[m] - best);
            int old = top1[row];
            if (bi != old) {
                atomicSub(&counts[old], 1);
                atomicAdd(&counts[bi], 1);
                top1[row] = bi;
            }
            gval[row] = 1.f / se;
        }
        __syncthreads();
    }
}

// fused offsets + tile-map + scatter (single block; LDS atomics)
__global__ __launch_bounds__(256) void osc_kernel(
    const int* __restrict__ counts,
    int* __restrict__ tm_e, int* __restrict__ tm_p, int* __restrict__ tm_end,
    const int* __restrict__ top1, int* __restrict__ brows)
{
    __shared__ int sbpos[NEXP];
    const int t = threadIdx.x;
    if (t == 0) {
        int run = 0, tile = 0;
        for (int e = 0; e < NEXP; ++e) {
            sbpos[e] = run;
            int beg = run, end = run + counts[e];
            for (int p = beg; p < end; p += 128) {
                tm_e[tile] = e; tm_p[tile] = p; tm_end[tile] = end; ++tile;
            }
            run = end;
        }
        for (; tile < NT128; ++tile) tm_e[tile] = -1;
    }
    __syncthreads();
    for (int i = t; i < NB; i += 256) {
        int e = top1[i];
        int pos = atomicAdd(&sbpos[e], 1);
        brows[pos] = i;
    }
}

// ---- expert GEMM1: h[pos][512] = relu(q[brows[pos]] @ w1[e]^T + b1[e]) ----
// 128x128 tile, 8 waves, 3-buf 48KB, counted vmcnt(2). grid (NT128, 4).
__global__ __launch_bounds__(512) void exp1_kernel(
    const unsigned short* __restrict__ qb, const unsigned short* __restrict__ ew1b,
    const float* __restrict__ eb1,
    const int* __restrict__ tm_e, const int* __restrict__ tm_p, const int* __restrict__ tm_end,
    const int* __restrict__ brows, unsigned short* __restrict__ h)
{
    const int e = tm_e[blockIdx.x];
    if (e < 0) return;                       // block-uniform: safe with barriers
    const int p0 = tm_p[blockIdx.x], end = tm_end[blockIdx.x];

    __shared__ unsigned short A[3][128][32];
    __shared__ unsigned short B[3][128][32];

    const int t = threadIdx.x, w = t >> 6, lane = t & 63;
    const int quad = lane >> 4, l16 = lane & 15;
    const int wr = w & 3, wc = w >> 2;
    const int c0 = blockIdx.y * 128;
    const unsigned short* w1p = ew1b + (size_t)e * HH * H;
    const int rl = lane >> 2, sl = lane & 3;

    // 16 chunks/kt, 2 per wave: c 0-7 A rows (gathered), 8-15 B rows
    const unsigned short* gsrc[2];
    unsigned short* lbase[2];
    #pragma unroll
    for (int j = 0; j < 2; ++j) {
        int c = w + j * 8;
        int rloc; const unsigned short* s; unsigned short* d;
        if (c < 8) {
            rloc = c * 16 + rl;
            int pa = p0 + rloc; if (pa >= end) pa = end - 1;   // ragged tail: duplicate last row
            s = qb + (size_t)brows[pa] * H;
            d = &A[0][c * 16][0];
        } else {
            rloc = (c - 8) * 16 + rl;
            s = w1p + (size_t)(c0 + rloc) * H;
            d = &B[0][(c - 8) * 16][0];
        }
        int f = (rloc & 3) ^ ((rloc >> 2) & 3);
        gsrc[j]  = s + (sl ^ f) * 8;
        lbase[j] = d;
    }
    const int bstr = 128 * 32;

    const f4 z4 = {0.f, 0.f, 0.f, 0.f};
    f4 acc[2][4] = {{z4, z4, z4, z4}, {z4, z4, z4, z4}};
    const int sw = (quad ^ (l16 & 3) ^ (l16 >> 2)) * 8;
    const int ra0 = wr * 32 + l16, ra1 = ra0 + 16;
    const int cbase = wc * 64;

    auto STAGE = [&](int buf, int kt) {
        #pragma unroll
        for (int j = 0; j < 2; ++j)
            gld16(gsrc[j] + kt * 32, lbase[j] + buf * bstr);
    };
    auto COMPUTE = [&](int buf) {
        bfrag a0 = *(const bfrag*)&A[buf][ra0][sw];
        bfrag a1 = *(const bfrag*)&A[buf][ra1][sw];
        #pragma unroll
        for (int cb = 0; cb < 4; ++cb) {
            bfrag bb = *(const bfrag*)&B[buf][cbase + cb * 16 + l16][sw];
            acc[0][cb] = MF(a0, bb, acc[0][cb]);
            acc[1][cb] = MF(a1, bb, acc[1][cb]);
        }
    };

    STAGE(0, 0);
    STAGE(1, 1);
    for (int kt = 0; kt < 32; ++kt) {
        if (kt < 31) asm volatile("s_waitcnt vmcnt(2)" ::: "memory");
        else         asm volatile("s_waitcnt vmcnt(0)" ::: "memory");
        __builtin_amdgcn_s_barrier();
        if (kt < 30) STAGE((kt + 2) % 3, kt + 2);
        COMPUTE(kt % 3);
    }

    const int prow0 = p0 + wr * 32;
    #pragma unroll
    for (int cb = 0; cb < 4; ++cb) {
        int col = c0 + cbase + cb * 16 + l16;
        float bias = eb1[e * HH + col];
        #pragma unroll
        for (int rb = 0; rb < 2; ++rb)
            #pragma unroll
            for (int i = 0; i < 4; ++i) {
                int row = rb * 16 + quad * 4 + i;
                if (prow0 + row < end)
                    h[(size_t)(prow0 + row) * HH + col] = f2bf(fmaxf(acc[rb][cb][i] + bias, 0.f));
            }
    }
}

// ---- expert GEMM2: v = h @ w2[e]^T + b2[e]; psum[row][slot] = partial sum v^2 ----
// 128x128 tile, 8 waves, 3-buf 48KB, counted vmcnt(2). grid (NT128, 8).
__global__ __launch_bounds__(512) void exp2_kernel(
    const unsigned short* __restrict__ h, const unsigned short* __restrict__ ew2b,
    const float* __restrict__ eb2,
    const int* __restrict__ tm_e, const int* __restrict__ tm_p, const int* __restrict__ tm_end,
    const int* __restrict__ brows,
    float* __restrict__ vout, float* __restrict__ psum)
{
    const int e = tm_e[blockIdx.x];
    if (e < 0) return;
    const int p0 = tm_p[blockIdx.x], end = tm_end[blockIdx.x];

    __shared__ unsigned short A[3][128][32];
    __shared__ unsigned short B[3][128][32];

    const int t = threadIdx.x, w = t >> 6, lane = t & 63;
    const int quad = lane >> 4, l16 = lane & 15;
    const int wr = w & 3, wc = w >> 2;
    const int c0 = blockIdx.y * 128;
    const unsigned short* w2p = ew2b + (size_t)e * H * HH;
    const int rl = lane >> 2, sl = lane & 3;

    const unsigned short* gsrc[2];
    unsigned short* lbase[2];
    #pragma unroll
    for (int j = 0; j < 2; ++j) {
        int c = w + j * 8;
        int rloc; const unsigned short* s; unsigned short* d;
        if (c < 8) {
            rloc = c * 16 + rl;
            int pa = p0 + rloc; if (pa >= end) pa = end - 1;
            s = h + (size_t)pa * HH;
            d = &A[0][c * 16][0];
        } else {
            rloc = (c - 8) * 16 + rl;
            s = w2p + (size_t)(c0 + rloc) * HH;
            d = &B[0][(c - 8) * 16][0];
        }
        int f = (rloc & 3) ^ ((rloc >> 2) & 3);
        gsrc[j]  = s + (sl ^ f) * 8;
        lbase[j] = d;
    }
    const int bstr = 128 * 32;

    const f4 z4 = {0.f, 0.f, 0.f, 0.f};
    f4 acc[2][4] = {{z4, z4, z4, z4}, {z4, z4, z4, z4}};
    const int sw = (quad ^ (l16 & 3) ^ (l16 >> 2)) * 8;
    const int ra0 = wr * 32 + l16, ra1 = ra0 + 16;
    const int cbase = wc * 64;

    auto STAGE = [&](int buf, int kt) {
        #pragma unroll
        for (int j = 0; j < 2; ++j)
            gld16(gsrc[j] + kt * 32, lbase[j] + buf * bstr);
    };
    auto COMPUTE = [&](int buf) {
        bfrag a0 = *(const bfrag*)&A[buf][ra0][sw];
        bfrag a1 = *(const bfrag*)&A[buf][ra1][sw];
        #pragma unroll
        for (int cb = 0; cb < 4; ++cb) {
            bfrag bb = *(const bfrag*)&B[buf][cbase + cb * 16 + l16][sw];
            acc[0][cb] = MF(a0, bb, acc[0][cb]);
            acc[1][cb] = MF(a1, bb, acc[1][cb]);
        }
    };

    STAGE(0, 0);
    STAGE(1, 1);
    for (int kt = 0; kt < 16; ++kt) {
        if (kt < 15) asm volatile("s_waitcnt vmcnt(2)" ::: "memory");
        else         asm volatile("s_waitcnt vmcnt(0)" ::: "memory");
        __builtin_amdgcn_s_barrier();
        if (kt < 14) STAGE((kt + 2) % 3, kt + 2);
        COMPUTE(kt % 3);
    }

    // bias + v-write + per-row sum(v^2); wave (wr,wc) owns rows p0+wr*32, cols c0+wc*64
    const int pw0 = p0 + wr * 32;
    const int slot = blockIdx.y * 2 + wc;   // 8 blocks x 2 col-halves = 16 psum slots
    float rs0[4] = {0.f, 0.f, 0.f, 0.f}, rs1[4] = {0.f, 0.f, 0.f, 0.f};
    #pragma unroll
    for (int i = 0; i < 4; ++i) {
        int row0i = quad * 4 + i, row1i = 16 + quad * 4 + i;
        int g0 = pw0 + row0i; if (g0 >= end) g0 = end - 1;
        int g1 = pw0 + row1i; if (g1 >= end) g1 = end - 1;
        int gr0 = brows[g0], gr1 = brows[g1];
        #pragma unroll
        for (int cb = 0; cb < 4; ++cb) {
            int col = c0 + cbase + cb * 16 + l16;
            float bias = eb2[e * H + col];
            float v0 = acc[0][cb][i] + bias;
            float v1 = acc[1][cb][i] + bias;
            vout[(size_t)gr0 * H + col] = v0;
            vout[(size_t)gr1 * H + col] = v1;
            rs0[i] += v0 * v0;
            rs1[i] += v1 * v1;
        }
    }
    #pragma unroll
    for (int i = 0; i < 4; ++i) {
        float s0 = rs0[i], s1 = rs1[i];
        #pragma unroll
        for (int off = 8; off; off >>= 1) {
            s0 += __shfl_xor(s0, off, 16);
            s1 += __shfl_xor(s1, off, 16);
        }
        if (l16 == 0) {
            int g0 = pw0 + quad * 4 + i;      if (g0 >= end) g0 = end - 1;
            int g1 = pw0 + 16 + quad * 4 + i; if (g1 >= end) g1 = end - 1;
            psum[(size_t)brows[g0] * 16 + slot] = s0;
            psum[(size_t)brows[g1] * 16 + slot] = s1;
        }
    }
}

// out = v * scale + q ; scale computed inline from psum (one block per row)
__global__ __launch_bounds__(256) void finalize_kernel(
    float* __restrict__ out, const float* __restrict__ q,
    const float* __restrict__ psum, const float* __restrict__ gval)
{
    const int row = blockIdx.x, t = threadIdx.x;
    float s = 0.f;
    #pragma unroll
    for (int j = 0; j < 16; ++j) s += psum[(size_t)row * 16 + j];
    float g = gval[row];
    float sc = g / fmaxf(g * sqrtf(s), 1e-6f);
    size_t i = (size_t)row * 256 + t;
    float4 v = ((const float4*)out)[i];
    float4 qq = ((const float4*)q)[i];
    float4 o;
    o.x = v.x * sc + qq.x;
    o.y = v.y * sc + qq.y;
    o.z = v.z * sc + qq.z;
    o.w = v.w * sc + qq.w;
    ((float4*)out)[i] = o;
}

extern "C" void kernel_launch(void* const* d_in, const int* in_sizes, int n_in,
                              void* d_out, int out_size, void* d_ws, size_t ws_size,
                              hipStream_t stream) {
    const float* q      = (const float*)d_in[0];
    const float* cls1_w = (const float*)d_in[1];
    const float* cls1_b = (const float*)d_in[2];
    const float* cls3_w = (const float*)d_in[3];
    const float* cls3_b = (const float*)d_in[4];
    const float* exp_w1 = (const float*)d_in[5];
    const float* exp_b1 = (const float*)d_in[6];
    const float* exp_w2 = (const float*)d_in[7];
    const float* exp_b2 = (const float*)d_in[8];
    float* out = (float*)d_out;

    // ---- workspace layout (~62 MB), lifetime-based aliasing ----
    char* w = (char*)d_ws;
    float* psum   = (float*)w;              w += (size_t)NB * 16 * 4;
    float* gvalp  = (float*)w;              w += (size_t)NB * 4;
    int* top1     = (int*)w;                w += (size_t)NB * 4;
    int* brows    = (int*)w;                w += (size_t)NB * 4;
    int* ambig_rows = (int*)w;              w += (size_t)NB * 4;
    int* counts   = (int*)w;                w += 16 * 4;
    int* ambig_cnt = (int*)w;               w += 4 * 4;
    int* tm_e     = (int*)w;                w += NT128 * 4;
    int* tm_p     = (int*)w;                w += NT128 * 4;
    int* tm_end   = (int*)w;                w += NT128 * 4;
    w = (char*)(((size_t)w + 15) & ~(size_t)15);
    unsigned short* qhi  = (unsigned short*)w;  w += (size_t)NB * H * 2;   // lives whole pipeline
    unsigned short* qlo  = (unsigned short*)w;  w += (size_t)NB * H * 2;   // dead after g1 -> ew2b
    unsigned short* x1hi = (unsigned short*)w;                              // dead after logits
    unsigned short* x1lo = x1hi + (size_t)NB * HH;  w += (size_t)NB * HH * 2 * 2;  // -> x1buf -> ew1b
    unsigned short* hbuf = (unsigned short*)w;  w += (size_t)NB * HH * 2;
    unsigned short* w1hi = (unsigned short*)w;  w += (size_t)HH * H * 2;
    unsigned short* w1lo = (unsigned short*)w;  w += (size_t)HH * H * 2;
    unsigned short* w3hi = (unsigned short*)w;  w += (size_t)NEXP * HH * 2;
    unsigned short* w3lo = (unsigned short*)w;  w += (size_t)NEXP * HH * 2;
    unsigned short* ew1b = x1hi;   // reused after logits+fixup
    unsigned short* ew2b = qlo;    // reused after g1
    float* x1buf = (float*)x1hi;   // fp32 fixup scratch aliasing dead x1hi/x1lo

    cvtA_kernel<<<8712, 256, 0, stream>>>(q, cls1_w, cls3_w, qhi, qlo, w1hi, w1lo,
                                          w3hi, w3lo, counts, ambig_cnt);
    g1_kernel<<<dim3(NB / 128, 4), 512, 0, stream>>>(qhi, qlo, w1hi, w1lo, cls1_b, x1hi, x1lo);
    logits_kernel<<<NB / 32, 256, 0, stream>>>(x1hi, x1lo, w3hi, w3lo, cls3_b,
                                               top1, gvalp, counts, ambig_rows, ambig_cnt);
    fixup1_kernel<<<256, 256, 0, stream>>>(q, cls1_w, cls1_b, ambig_rows, ambig_cnt, x1buf);
    fixup2_kernel<<<64, 256, 0, stream>>>(x1buf, cls3_w, cls3_b, ambig_rows, ambig_cnt,
                                          top1, gvalp, counts);
    cvtB_kernel<<<16384, 256, 0, stream>>>(exp_w1, exp_w2, ew1b, ew2b);
    osc_kernel<<<1, 256, 0, stream>>>(counts, tm_e, tm_p, tm_end, top1, brows);
    exp1_kernel<<<dim3(NT128, 4), 512, 0, stream>>>(qhi, ew1b, exp_b1,
                                                    tm_e, tm_p, tm_end, brows, hbuf);
    exp2_kernel<<<dim3(NT128, 8), 512, 0, stream>>>(hbuf, ew2b, exp_b2,
                                                    tm_e, tm_p, tm_end, brows, out, psum);
    finalize_kernel<<<NB, 256, 0, stream>>>(out, q, psum, gvalp);
}